// Round 3
// baseline (342.364 us; speedup 1.0000x reference)
//
#include <hip/hip_runtime.h>
#include <hip/hip_bf16.h>
#include <math.h>

typedef unsigned short u16;
typedef short bf16x8 __attribute__((ext_vector_type(8)));
typedef float f32x4 __attribute__((ext_vector_type(4)));
typedef float f32x16 __attribute__((ext_vector_type(16)));

__device__ __forceinline__ u16 f2b(float f){
  union { float f; unsigned u; } c; c.f = f;
  unsigned u = c.u;
  unsigned r = (u + 0x7fffu + ((u >> 16) & 1u)) >> 16;
  return (u16)r;
}
__device__ __forceinline__ unsigned pack2(float a, float b){
  return (unsigned)f2b(a) | ((unsigned)f2b(b) << 16);
}
__device__ __forceinline__ float gelu_f(float x){
  return 0.5f * x * (1.0f + erff(x * 0.70710678118654752f));
}
// async global->LDS 16B DMA; lds dest must be wave-uniform base + lane*16
__device__ __forceinline__ void dma16(const void* g, void* l){
  __builtin_amdgcn_global_load_lds(
      (const __attribute__((address_space(1))) unsigned*)g,
      (__attribute__((address_space(3))) unsigned*)l, 16, 0, 0);
}

// ---------------------------------------------------------------------------
// Weight prep -> bf16 [N][K] row-major. Layout in wT (u16 elements):
//   WprojT @ 0 (128x128) | QKVT @ 16384 (2 x [1536][128], rows 0-511 q,
//   512-1023 k, 1024-1535 v) | WhT @ 409600 (2 x [128][512]) |
//   WfcT @ 540672 (2 x [128][128]) | WcT @ 573440 ([512][128])
// Tail gids zero the stats (384 f32) and T (9216 f32) buffers.
// ---------------------------------------------------------------------------
__global__ __launch_bounds__(256) void prep_weights(
    const float* __restrict__ Wproj, const float* __restrict__ Wq,
    const float* __restrict__ Wk,    const float* __restrict__ Wv,
    const float* __restrict__ Wh,    const float* __restrict__ Wfc,
    const float* __restrict__ Wc,    u16* __restrict__ wT,
    float* __restrict__ stats, float* __restrict__ Tbuf)
{
  int gid = blockIdx.x * 256 + threadIdx.x;
  if (gid >= 648576) return;
  if (gid >= 638976) {
    int o = gid - 638976;
    if (o < 384) stats[o] = 0.0f; else Tbuf[o - 384] = 0.0f;
    return;
  }
  float val;
  if (gid < 16384) {
    int n = gid >> 7, k = gid & 127;
    val = Wproj[k * 128 + n];
  } else if (gid < 409600) {               // fused QKV^T
    int o = gid - 16384; int l = o / 196608, oo = o - l * 196608;
    int n = oo >> 7, k = oo & 127;
    if (n < 512)       val = Wq[l * 65536 + k * 512 + n];
    else if (n < 1024) val = Wk[l * 65536 + k * 512 + (n - 512)];
    else               val = Wv[l * 65536 + k * 512 + (n - 1024)];
  } else if (gid < 540672) {               // WhT[l][n][k], in [512][128]
    int o = gid - 409600; int l = o >> 16, oo = o & 65535;
    int n = oo >> 9, k = oo & 511;
    val = Wh[l * 65536 + k * 128 + n];
  } else if (gid < 573440) {               // WfcT
    int o = gid - 540672; int l = o >> 14, oo = o & 16383;
    int n = oo >> 7, k = oo & 127;
    val = Wfc[l * 16384 + k * 128 + n];
  } else {                                 // WcT[n][k], in [128][512]
    int o = gid - 573440; int n = o >> 7, k = o & 127;
    val = Wc[k * 512 + n];
  }
  wT[gid] = f2b(val);
}

// ---------------------------------------------------------------------------
// Generic GEMM: C[M x N] = A[M x K] @ Bt[N x K]^T. 64x64 tile, 256 thr.
// A-staging: mode 1 -> from f32 x (f2b + row-validity computed in-block);
//            stA != null -> from f32 Af, normalized with per-set stats;
//            else bf16 A.
// Epilogue modes:
//  1 GELU_MASK : g=gelu(acc)*valid -> outf, outb              (N=128)
//  4 ADD_MASK  : u=hin'+acc*valid -> outf, + stats atomics    (N=128)
//  5 GELU_ADD  : u=hin'+gelu(acc)*valid -> outf, + stats      (N=128)
//     (hin' = hst ? normalize(hin, hst) : hin)
//  6 QKV split : c<512 -> q[s][h][m][d]; <1024 -> k; else vT[s][h][d][m]
// ---------------------------------------------------------------------------
__global__ __launch_bounds__(256) void gemm_bt(
    const u16* __restrict__ A, const float* __restrict__ Af,
    const float* __restrict__ stA, const u16* __restrict__ Bt,
    float* __restrict__ outf, u16* __restrict__ outb,
    u16* __restrict__ outb2, u16* __restrict__ outb3,
    const float* __restrict__ hin, const float* __restrict__ hst,
    float* __restrict__ valid, float* __restrict__ stats,
    const int* __restrict__ xsize, int N, int K, int mode)
{
  __shared__ __align__(16) u16 As[64 * 136];
  __shared__ __align__(16) u16 Bs[64 * 136];
  __shared__ float red[8];
  __shared__ float svalid[64];
  int tid = threadIdx.x;
  int wave = tid >> 6, lane = tid & 63, quad = lane >> 4, l16 = lane & 15;
  int bm = blockIdx.x, bn = blockIdx.y;
  int wm = (wave >> 1) * 32, wn = (wave & 1) * 32;
  int sset = bm >> 1;
  float amean = 0.f, ainv = 0.f, hmean = 0.f, hinv = 0.f;
  if (stA) {
    float S1 = stA[sset * 2], S2 = stA[sset * 2 + 1];
    int sz = xsize[sset]; if (sz < 1) sz = 1;
    float den = (float)sz * 128.0f;
    float mu = S1 / den; float var = S2 / den - mu * mu; if (var < 0.f) var = 0.f;
    amean = mu; ainv = 1.0f / (sqrtf(var) + 1e-8f);
  }
  if (hst) {
    float S1 = hst[sset * 2], S2 = hst[sset * 2 + 1];
    int sz = xsize[sset]; if (sz < 1) sz = 1;
    float den = (float)sz * 128.0f;
    float mu = S1 / den; float var = S2 / den - mu * mu; if (var < 0.f) var = 0.f;
    hmean = mu; hinv = 1.0f / (sqrtf(var) + 1e-8f);
  }
  f32x4 acc[2][2] = {};
  int nk = K >> 7;
  for (int kk = 0; kk < nk; ++kk) {
    for (int i = 0; i < 4; ++i) {
      int ch = tid + i * 256;
      int r = ch >> 4, cc = ch & 15;
      int row = bm * 64 + r;
      if (mode == 1) {                       // stage from f32 x + validity
        const float* p = Af + (size_t)row * 128 + cc * 8;
        float4 u0 = *(const float4*)p;
        float4 u1 = *(const float4*)(p + 4);
        int nz = (u0.x != 0.f) | (u0.y != 0.f) | (u0.z != 0.f) | (u0.w != 0.f) |
                 (u1.x != 0.f) | (u1.y != 0.f) | (u1.z != 0.f) | (u1.w != 0.f);
        nz |= __shfl_xor(nz, 1, 64); nz |= __shfl_xor(nz, 2, 64);
        nz |= __shfl_xor(nz, 4, 64); nz |= __shfl_xor(nz, 8, 64);
        if ((tid & 15) == 0) {
          svalid[r] = nz ? 1.0f : 0.0f;
          if (bn == 0) valid[row] = nz ? 1.0f : 0.0f;
        }
        uint4 w;
        w.x = pack2(u0.x, u0.y); w.y = pack2(u0.z, u0.w);
        w.z = pack2(u1.x, u1.y); w.w = pack2(u1.z, u1.w);
        *(uint4*)(As + r * 136 + cc * 8) = w;
      } else if (stA) {                      // stage normalized f32 h
        const float* p = Af + (size_t)row * 128 + cc * 8;
        float vl = valid[row] * ainv;
        float4 u0 = *(const float4*)p;
        float4 u1 = *(const float4*)(p + 4);
        uint4 w;
        w.x = pack2((u0.x - amean) * vl, (u0.y - amean) * vl);
        w.y = pack2((u0.z - amean) * vl, (u0.w - amean) * vl);
        w.z = pack2((u1.x - amean) * vl, (u1.y - amean) * vl);
        w.w = pack2((u1.z - amean) * vl, (u1.w - amean) * vl);
        *(uint4*)(As + r * 136 + cc * 8) = w;
      } else {
        *(uint4*)(As + r * 136 + cc * 8) =
            *(const uint4*)(A + (size_t)row * K + kk * 128 + cc * 8);
      }
      *(uint4*)(Bs + r * 136 + cc * 8) =
          *(const uint4*)(Bt + (size_t)(bn * 64 + r) * K + kk * 128 + cc * 8);
    }
    __syncthreads();
    for (int ks = 0; ks < 4; ++ks) {
      bf16x8 aF[2], bF[2];
      for (int i = 0; i < 2; ++i)
        aF[i] = *(const bf16x8*)(As + (wm + i * 16 + l16) * 136 + ks * 32 + quad * 8);
      for (int j = 0; j < 2; ++j)
        bF[j] = *(const bf16x8*)(Bs + (wn + j * 16 + l16) * 136 + ks * 32 + quad * 8);
      for (int i = 0; i < 2; ++i)
        for (int j = 0; j < 2; ++j)
          acc[i][j] = __builtin_amdgcn_mfma_f32_16x16x32_bf16(aF[i], bF[j], acc[i][j], 0, 0, 0);
    }
    __syncthreads();
  }
  float ls1 = 0.f, ls2 = 0.f;
  for (int i = 0; i < 2; ++i)
    for (int j = 0; j < 2; ++j)
      for (int g = 0; g < 4; ++g) {
        int rl = wm + i * 16 + quad * 4 + g;
        int r = bm * 64 + rl;
        int c = bn * 64 + wn + j * 16 + l16;
        float a = acc[i][j][g];
        if (mode == 1) {
          float gg = gelu_f(a) * svalid[rl];
          outf[(size_t)r * 128 + c] = gg;
          outb[(size_t)r * 128 + c] = f2b(gg);
        } else if (mode == 4 || mode == 5) {
          float add = (mode == 5) ? gelu_f(a) : a;
          float vl = valid[r];
          float hv = hin[(size_t)r * 128 + c];
          if (hst) hv = (hv - hmean) * hinv * vl;
          float u = hv + add * vl;
          outf[(size_t)r * 128 + c] = u;
          ls1 += u; ls2 += u * u;
        } else { // mode 6
          int s = r >> 7, m = r & 127;
          if (c < 512) {
            int hh = c >> 7, d = c & 127;
            outb[(size_t)(((s * 4 + hh) * 128 + m)) * 128 + d] = f2b(a);
          } else if (c < 1024) {
            int c2 = c - 512, hh = c2 >> 7, d = c2 & 127;
            outb2[(size_t)(((s * 4 + hh) * 128 + m)) * 128 + d] = f2b(a);
          } else {
            int c2 = c - 1024, hh = c2 >> 7, d = c2 & 127;
            outb3[(size_t)(((s * 4 + hh) * 128 + d)) * 128 + m] = f2b(a);
          }
        }
      }
  if (mode == 4 || mode == 5) {
    for (int off = 1; off < 64; off <<= 1) {
      ls1 += __shfl_xor(ls1, off, 64);
      ls2 += __shfl_xor(ls2, off, 64);
    }
    if (lane == 0) { red[wave * 2] = ls1; red[wave * 2 + 1] = ls2; }
    __syncthreads();
    if (tid == 0) {
      float S1 = red[0] + red[2] + red[4] + red[6];
      float S2 = red[1] + red[3] + red[5] + red[7];
      atomicAdd(stats + sset * 2, S1);
      atomicAdd(stats + sset * 2 + 1, S2);
    }
  }
}

// ---------------------------------------------------------------------------
// Attention per (set, head), size-trimmed (unchanged from passing round-2).
// ---------------------------------------------------------------------------
__global__ __launch_bounds__(256) void attn_kernel(
    const u16* __restrict__ qg, const u16* __restrict__ kg,
    const u16* __restrict__ vTg, u16* __restrict__ og,
    const int* __restrict__ xsize)
{
  __shared__ __align__(16) u16 bufA[128 * 136];
  __shared__ __align__(16) u16 bufB[128 * 136];
  int tid = threadIdx.x, wave = tid >> 6, lane = tid & 63, quad = lane >> 4, l16 = lane & 15;
  int bid = blockIdx.x;
  int s = bid >> 2, hh = bid & 3;
  int sz = xsize[s]; if (sz < 1) sz = 1;
  int Mt = (sz + 15) >> 4;
  int Mk = (sz + 31) >> 5;
  size_t base = (size_t)bid * 16384;
  for (int t = 0; t < 8; ++t) {
    if (t < Mt) {
      int ch = tid + t * 256; int r = ch >> 4, cc = ch & 15;
      *(uint4*)(bufA + r * 136 + cc * 8) = *(const uint4*)(qg + base + r * 128 + cc * 8);
      *(uint4*)(bufB + r * 136 + cc * 8) = *(const uint4*)(kg + base + r * 128 + cc * 8);
    }
  }
  __syncthreads();
  int wm = wave * 32;
  bool act0 = (wave * 2) < Mt, act1 = (wave * 2 + 1) < Mt;
  f32x4 acc[2][8] = {};
  if (act0 || act1) {
    for (int ks = 0; ks < 4; ++ks) {
      bf16x8 aF[2], bF[8];
      if (act0) aF[0] = *(const bf16x8*)(bufA + (wm + l16) * 136 + ks * 32 + quad * 8);
      if (act1) aF[1] = *(const bf16x8*)(bufA + (wm + 16 + l16) * 136 + ks * 32 + quad * 8);
#pragma unroll
      for (int j = 0; j < 8; ++j)
        if (j < Mt) bF[j] = *(const bf16x8*)(bufB + (j * 16 + l16) * 136 + ks * 32 + quad * 8);
#pragma unroll
      for (int j = 0; j < 8; ++j)
        if (j < Mt) {
          if (act0) acc[0][j] = __builtin_amdgcn_mfma_f32_16x16x32_bf16(aF[0], bF[j], acc[0][j], 0, 0, 0);
          if (act1) acc[1][j] = __builtin_amdgcn_mfma_f32_16x16x32_bf16(aF[1], bF[j], acc[1][j], 0, 0, 0);
        }
    }
  }
  const float rs = 0.08838834764831845f;
  for (int i = 0; i < 2; ++i) {
    bool act = i ? act1 : act0;
    if (!act) continue;
    for (int g = 0; g < 4; ++g) {
      int rl = wm + i * 16 + quad * 4 + g;
      float vals[8]; float rmax = -1e30f;
#pragma unroll
      for (int j = 0; j < 8; ++j)
        if (j < Mt) {
          float v = acc[i][j][g] * rs;
          vals[j] = v;
          rmax = fmaxf(rmax, v);
        }
      for (int off = 1; off < 16; off <<= 1) rmax = fmaxf(rmax, __shfl_xor(rmax, off, 64));
      if (sz < 128) rmax = fmaxf(rmax, 0.0f);
      float rsum = 0.f;
#pragma unroll
      for (int j = 0; j < 8; ++j)
        if (j < Mt) {
          float e = (vals[j] != 0.0f) ? expf(vals[j] - rmax) : 0.0f;
          vals[j] = e; rsum += e;
        }
      for (int off = 1; off < 16; off <<= 1) rsum += __shfl_xor(rsum, off, 64);
      float inv = 1.0f / (rsum + 1e-10f);
#pragma unroll
      for (int j = 0; j < 8; ++j)
        if (j < Mt) bufA[rl * 136 + j * 16 + l16] = f2b(vals[j] * inv);
    }
  }
  __syncthreads();
  for (int t = 0; t < 8; ++t) {
    int ch = tid + t * 256; int r = ch >> 4, cc = ch & 15;
    *(uint4*)(bufB + r * 136 + cc * 8) = *(const uint4*)(vTg + base + r * 128 + cc * 8);
  }
  __syncthreads();
  f32x4 acc2[2][8] = {};
  if (act0 || act1) {
    for (int ks = 0; ks < Mk; ++ks) {
      bf16x8 aF[2], bF[8];
      if (act0) aF[0] = *(const bf16x8*)(bufA + (wm + l16) * 136 + ks * 32 + quad * 8);
      if (act1) aF[1] = *(const bf16x8*)(bufA + (wm + 16 + l16) * 136 + ks * 32 + quad * 8);
#pragma unroll
      for (int j = 0; j < 8; ++j)
        bF[j] = *(const bf16x8*)(bufB + (j * 16 + l16) * 136 + ks * 32 + quad * 8);
#pragma unroll
      for (int j = 0; j < 8; ++j) {
        if (act0) acc2[0][j] = __builtin_amdgcn_mfma_f32_16x16x32_bf16(aF[0], bF[j], acc2[0][j], 0, 0, 0);
        if (act1) acc2[1][j] = __builtin_amdgcn_mfma_f32_16x16x32_bf16(aF[1], bF[j], acc2[1][j], 0, 0, 0);
      }
    }
  }
  for (int i = 0; i < 2; ++i)
    for (int j = 0; j < 8; ++j)
      for (int g = 0; g < 4; ++g) {
        int rl = wm + i * 16 + quad * 4 + g;
        int d = j * 16 + l16;
        og[(size_t)(s * 128 + rl) * 512 + hh * 128 + d] = f2b(acc2[i][j][g]);
      }
}

// ---------------------------------------------------------------------------
// Cross-set v3: persistent blocks. Grid (48 j, 2 parity, 4 h). Block loads
// z_j once, loops i = j+parity, j+parity+2, ... with double-buffered async
// z_i (global_load_lds). Per pair each wave atomicAdds its partial of the
// raw symmetric sum T[j,i,h] = sum_{m,n} leaky(z_j[m]·z_i[n])/sqrt(128).
// Fragment-order LDS chunks (lane-linear => DMA-compatible, conflict-free).
// ---------------------------------------------------------------------------
__global__ __launch_bounds__(256) void cross_kernel(
    const u16* __restrict__ zg, float* __restrict__ Tbuf, const int* __restrict__ xsize)
{
  __shared__ __align__(16) u16 bufA[16384];
  __shared__ __align__(16) u16 bufB[2][16384];
  int tid = threadIdx.x, wave = tid >> 6, lane = tid & 63;
  int j = blockIdx.x, half = blockIdx.y, hh = blockIdx.z;
  int sj = xsize[j]; if (sj < 1) sj = 1;
  int MjT = (sj + 31) >> 5;
  // DMA z_j -> bufA
  {
    const u16* src = zg + (((size_t)j * 4 + hh) << 14);
#pragma unroll
    for (int t = 0; t < 8; ++t)
      if ((t >> 1) < MjT) {
        int c = t * 256 + tid;
        int m = c & 31, ha = (c >> 5) & 1, ks = (c >> 6) & 7, g = c >> 9;
        dma16(src + (g * 32 + m) * 128 + ks * 16 + ha * 8, bufA + c * 8);
      }
  }
  int i0 = j + half;
  int MiT = 0;
  if (i0 < 48) {
    int si = xsize[i0]; if (si < 1) si = 1; MiT = (si + 31) >> 5;
    const u16* src = zg + (((size_t)i0 * 4 + hh) << 14);
#pragma unroll
    for (int t = 0; t < 8; ++t)
      if ((t >> 1) < MiT) {
        int c = t * 256 + tid;
        int m = c & 31, ha = (c >> 5) & 1, ks = (c >> 6) & 7, g = c >> 9;
        dma16(src + (g * 32 + m) * 128 + ks * 16 + ha * 8, bufB[0] + c * 8);
      }
  }
  __syncthreads();
  int gA = (wave >> 1) * 2, gB = (wave & 1) * 2;
  bool a0 = gA < MjT, a1 = (gA + 1) < MjT;
  const float rs = 0.08838834764831845f;
  int buf = 0;
  for (int i = i0; i < 48; i += 2) {
    int inx = i + 2, Mnx = 0;
    if (inx < 48) {
      int sn = xsize[inx]; if (sn < 1) sn = 1; Mnx = (sn + 31) >> 5;
      const u16* src = zg + (((size_t)inx * 4 + hh) << 14);
#pragma unroll
      for (int t = 0; t < 8; ++t)
        if ((t >> 1) < Mnx) {
          int c = t * 256 + tid;
          int m = c & 31, ha = (c >> 5) & 1, ks = (c >> 6) & 7, g = c >> 9;
          dma16(src + (g * 32 + m) * 128 + ks * 16 + ha * 8, bufB[buf ^ 1] + c * 8);
        }
    }
    const u16* zb = bufB[buf];
    bool b0 = gB < MiT, b1 = (gB + 1) < MiT;
    f32x16 acc[2][2] = {};
    if ((a0 || a1) && (b0 || b1)) {
      for (int ks = 0; ks < 8; ++ks) {
        bf16x8 aF[2], bF[2];
        if (a0) aF[0] = *(const bf16x8*)(bufA + ((gA    ) * 8 + ks) * 512 + lane * 8);
        if (a1) aF[1] = *(const bf16x8*)(bufA + ((gA + 1) * 8 + ks) * 512 + lane * 8);
        if (b0) bF[0] = *(const bf16x8*)(zb   + ((gB    ) * 8 + ks) * 512 + lane * 8);
        if (b1) bF[1] = *(const bf16x8*)(zb   + ((gB + 1) * 8 + ks) * 512 + lane * 8);
        if (a0 && b0) acc[0][0] = __builtin_amdgcn_mfma_f32_32x32x16_bf16(aF[0], bF[0], acc[0][0], 0, 0, 0);
        if (a0 && b1) acc[0][1] = __builtin_amdgcn_mfma_f32_32x32x16_bf16(aF[0], bF[1], acc[0][1], 0, 0, 0);
        if (a1 && b0) acc[1][0] = __builtin_amdgcn_mfma_f32_32x32x16_bf16(aF[1], bF[0], acc[1][0], 0, 0, 0);
        if (a1 && b1) acc[1][1] = __builtin_amdgcn_mfma_f32_32x32x16_bf16(aF[1], bF[1], acc[1][1], 0, 0, 0);
      }
    }
    float s1 = 0.f, s2 = 0.f;
#pragma unroll
    for (int ii = 0; ii < 2; ++ii)
#pragma unroll
      for (int jj = 0; jj < 2; ++jj)
#pragma unroll
        for (int r = 0; r < 16; ++r) {
          float a = acc[ii][jj][r];
          s1 += a; s2 += fabsf(a);
        }
    float tp = rs * (0.65f * s1 + 0.35f * s2);
    for (int off = 1; off < 64; off <<= 1) tp += __shfl_xor(tp, off, 64);
    if (lane == 0) atomicAdd(Tbuf + ((j * 48 + i) << 2) + hh, tp);
    __syncthreads();
    MiT = Mnx; buf ^= 1;
  }
}

// out[a][b] = sum_h T[min,max,h] * w2[h] / (size_b * 128)
__global__ __launch_bounds__(256) void final_kernel(
    const float* __restrict__ Tbuf, const float* __restrict__ w2,
    const int* __restrict__ xsize, float* __restrict__ out)
{
  int idx = blockIdx.x * 256 + threadIdx.x;
  if (idx >= 2304) return;
  int a = idx / 48, b = idx - a * 48;
  int j = a < b ? a : b, i = a < b ? b : a;
  float t = 0.f;
  for (int h = 0; h < 4; ++h) t += Tbuf[((j * 48 + i) << 2) + h] * w2[h];
  int szb = xsize[b]; if (szb < 1) szb = 1;
  out[idx] = t / ((float)szb * 128.0f);
}

// ---------------------------------------------------------------------------
extern "C" void kernel_launch(void* const* d_in, const int* in_sizes, int n_in,
                              void* d_out, int out_size, void* d_ws, size_t ws_size,
                              hipStream_t stream)
{
  const float* x     = (const float*)d_in[0];
  const int*   xsize = (const int*)d_in[1];
  const float* Wproj = (const float*)d_in[2];
  const float* Wq    = (const float*)d_in[3];
  const float* Wk    = (const float*)d_in[4];
  const float* Wv    = (const float*)d_in[5];
  const float* Wh    = (const float*)d_in[6];
  const float* Wfc   = (const float*)d_in[7];
  const float* Wc    = (const float*)d_in[8];
  const float* w2    = (const float*)d_in[9];
  float* out = (float*)d_out;

  char* ws = (char*)d_ws;
  size_t off = 0;
  auto alloc = [&](size_t bytes) -> char* {
    char* p = ws + off;
    off += (bytes + 255) & ~(size_t)255;
    return p;
  };
  u16*   wT    = (u16*)  alloc(638976 * 2);
  float* stats = (float*)alloc(384 * 4);          // 4 stages x 48 sets x {S1,S2}
  float* Tbuf  = (float*)alloc(9216 * 4);         // raw cross sums
  float* valid = (float*)alloc(6144 * 4);
  float* hf0   = (float*)alloc(6144 * 128 * 4);   // proj output (f32)
  u16*   hb    = (u16*)  alloc(6144 * 128 * 2);   // proj output (bf16)
  float* ufA   = (float*)alloc(6144 * 128 * 4);
  float* ufB   = (float*)alloc(6144 * 128 * 4);
  u16*   qb    = (u16*)  alloc((size_t)3145728 * 2);
  u16*   kb    = (u16*)  alloc((size_t)3145728 * 2);
  u16*   vTb   = (u16*)  alloc((size_t)3145728 * 2);
  u16*   ob    = (u16*)  alloc((size_t)6144 * 512 * 2);

  float* st00 = stats +   0;
  float* st01 = stats +  96;
  float* st10 = stats + 192;
  float* st11 = stats + 288;

  prep_weights<<<2534, 256, 0, stream>>>(Wproj, Wq, Wk, Wv, Wh, Wfc, Wc, wT, stats, Tbuf);

  // h0 = gelu(x @ Wproj) * mask ; also computes valid[]
  gemm_bt<<<dim3(96, 2), 256, 0, stream>>>(nullptr, x, nullptr, wT,
                                           hf0, hb, nullptr, nullptr,
                                           nullptr, nullptr, valid, nullptr, xsize,
                                           128, 128, 1);
  // ---- layer 0 ----
  gemm_bt<<<dim3(96, 24), 256, 0, stream>>>(hb, nullptr, nullptr, wT + 16384,
                                            nullptr, qb, kb, vTb,
                                            nullptr, nullptr, valid, nullptr, xsize,
                                            1536, 128, 6);
  attn_kernel<<<192, 256, 0, stream>>>(qb, kb, vTb, ob, xsize);
  gemm_bt<<<dim3(96, 2), 256, 0, stream>>>(ob, nullptr, nullptr, wT + 409600,
                                           ufA, nullptr, nullptr, nullptr,
                                           hf0, nullptr, valid, st00, xsize,
                                           128, 512, 4);
  gemm_bt<<<dim3(96, 2), 256, 0, stream>>>(nullptr, ufA, st00, wT + 540672,
                                           ufB, nullptr, nullptr, nullptr,
                                           ufA, st00, valid, st01, xsize,
                                           128, 128, 5);
  // ---- layer 1 ----
  gemm_bt<<<dim3(96, 24), 256, 0, stream>>>(nullptr, ufB, st01, wT + 16384 + 196608,
                                            nullptr, qb, kb, vTb,
                                            nullptr, nullptr, valid, nullptr, xsize,
                                            1536, 128, 6);
  attn_kernel<<<192, 256, 0, stream>>>(qb, kb, vTb, ob, xsize);
  gemm_bt<<<dim3(96, 2), 256, 0, stream>>>(ob, nullptr, nullptr, wT + 409600 + 65536,
                                           ufA, nullptr, nullptr, nullptr,
                                           ufB, st01, valid, st10, xsize,
                                           128, 512, 4);
  gemm_bt<<<dim3(96, 2), 256, 0, stream>>>(nullptr, ufA, st10, wT + 540672 + 16384,
                                           ufB, nullptr, nullptr, nullptr,
                                           ufA, st10, valid, st11, xsize,
                                           128, 128, 5);
  // ---- cross-set score ----
  gemm_bt<<<dim3(96, 8), 256, 0, stream>>>(nullptr, ufB, st11, wT + 573440,
                                           nullptr, qb, qb, qb,
                                           nullptr, nullptr, valid, nullptr, xsize,
                                           512, 128, 6);
  cross_kernel<<<dim3(48, 2, 4), 256, 0, stream>>>(qb, Tbuf, xsize);
  final_kernel<<<9, 256, 0, stream>>>(Tbuf, w2, xsize, out);
}